// Round 1
// baseline (122.272 us; speedup 1.0000x reference)
//
#include <hip/hip_runtime.h>
#include <hip/hip_bf16.h>
#include <math.h>

#define KW 5
#define BETA 15.0f
#define MSHIFT 3.0f
#define CIN 8
#define COUT 8
#define HH 256
#define WW 256
#define TWW 16     // wave tile width  (one 16-px MFMA N-group)
#define TWH 8      // wave tile height
#define WCW 20     // TWW + 4 halo
#define WCH 12     // TWH + 4 halo (rows 0..11 serve hl+tr up to 6+5=11)
#define WSLOTS (WCW * WCH)   // 240 slots/wave
#define NG 8       // K-groups: k=(tr 0..5, tc 0..4, c 0..7) = 240 pad 256

typedef float f32x4 __attribute__((ext_vector_type(4)));
typedef short s16x8 __attribute__((ext_vector_type(8)));

static __device__ __forceinline__ unsigned f2bf(float f) {
    unsigned u = __float_as_uint(f);
    return (u + 0x7FFFu + ((u >> 16) & 1u)) >> 16;  // RNE
}

// Exp-space 5x5 conv as implicit GEMM, wave-autonomous (R8), 2-row-packed (R9):
// out = M + log(sum exp(beta(x-M)) * exp(beta w)) / beta.
//
// R10: build_afrag pre-kernel REMOVED. The A-fragment table (exact MFMA
// A-layout, 2-row-packed) is recomputed per-thread from wgt (6.4 KB, L1-hot):
//   rows 0-7 : A[o][k=(tr,tc,c)] = exp(beta*w[o][c][tr,tc])   (tr<=4; 0 at tr=5)
//   rows 8-15: A[8+o][k]         = exp(beta*w[o][c][tr-1,tc]) (tr>=1; 0 at tr=0)
// With B[k][px] = EX[hl+tr][px+tc][c], D rows 0-7 = out row hl, rows 8-15 =
// out row hl+1 (index shift Sum_tr W[tr-1] EX[hl+tr] = Sum W[tr'] EX[hl+1+tr']).
// Cost: 64 L1-hot dword loads + 64 v_exp per thread, once per block, placed
// BEFORE the staging loop so temporaries don't stack on staging's live range.
// Saves: one serialized graph node (~2-4 us) + 32 KB/block of L2 table reads.
// Workspace d_ws is now unused.
//
// Per hl-pair: 8 ds_read_b128 + 8 MFMA -> 16 px * 2 rows * 8 o. Epilogue
// full-exec: quad -> (dh=quad>>1, o=(quad&1)*4+reg).
// launch_bounds min-waves 5 -> ~102-VGPR cap (need ~85). NEVER 8: 64-cap
// spilled afrag in R4/R5 (VGPR_Count 32, 2-4x hbm traffic).
__global__ __launch_bounds__(256, 5) void morph_mfma(
    const float* __restrict__ x, const float* __restrict__ wgt,
    float* __restrict__ out)
{
    __shared__ int4 exs[4 * WSLOTS];   // 4 waves * 3840 B = 15360 B

    const int tid  = threadIdx.x;
    const int lane = tid & 63;
    const int wv   = tid >> 6;
    const int px   = lane & 15;
    const int quad = lane >> 4;
    const int row  = lane & 15;

    // XCD-contiguous swizzle: 2048 blocks = 8 XCD * 256; XCD k gets 2 batches.
    const int lid = blockIdx.x;
    const int sw  = (lid & 7) * 256 + (lid >> 3);
    const int b   = sw >> 7;
    const int t   = sw & 127;                 // 32 h-tiles * 4 w-tiles
    const int h0  = (t >> 2) * TWH;
    const int w0  = (t & 3) * 64 + wv * TWW;  // this wave's 16-px column

    int4* myex = &exs[wv * WSLOTS];

    // ---- A fragments: in-register compute from wgt (was build_afrag) ----
    s16x8 afrag[NG];
    int   toff[NG];
    #pragma unroll
    for (int g = 0; g < NG; ++g) {
        int tap30 = g * 4 + quad;
        int tr = tap30 / KW, tc = tap30 % KW;
        s16x8 af;
        #pragma unroll
        for (int j = 0; j < CIN; ++j) {          // j = c
            float v = 0.0f;
            if (tap30 < 30) {
                if (row < COUT) {
                    if (tr <= 4)
                        v = __expf(BETA * wgt[(row * CIN + j) * (KW * KW) + tr * KW + tc]);
                } else {
                    if (tr >= 1)
                        v = __expf(BETA * wgt[((row - 8) * CIN + j) * (KW * KW) + (tr - 1) * KW + tc]);
                }
            }
            af[j] = (short)f2bf(v);
        }
        afrag[g] = af;
        int tcl = tap30 < 30 ? tap30 : 29;       // clamp addr; A=0 kills pads
        toff[g] = (tcl / KW) * WCW + (tcl % KW);
    }

    // ---- stage exp(beta*(x-M)) for THIS WAVE's 20x12 halo ----
    for (int s = lane; s < WSLOTS; s += 64) {
        int r = s / WCW, col = s - r * WCW;
        int gh = h0 + r - 2, gw = w0 + col - 2;
        bool ok = ((unsigned)gh < (unsigned)HH) & ((unsigned)gw < (unsigned)WW);
        unsigned pk[4];
        #pragma unroll
        for (int c2 = 0; c2 < 4; ++c2) {
            float v0 = 0.0f, v1 = 0.0f;
            if (ok) {
                v0 = x[((b * CIN + 2 * c2) * HH + gh) * WW + gw];
                v1 = x[((b * CIN + 2 * c2 + 1) * HH + gh) * WW + gw];
            }
            // exp(beta*(v-M)) = 2^(v*beta*log2e - beta*M*log2e): 1 fma + v_exp
            float2 e = make_float2(
                __builtin_amdgcn_exp2f(fmaf(v0, 21.6404256f, -64.9212768f)),
                __builtin_amdgcn_exp2f(fmaf(v1, 21.6404256f, -64.9212768f)));
            __hip_bfloat162 h2 = __float22bfloat162_rn(e);
            pk[c2] = *reinterpret_cast<unsigned*>(&h2);
        }
        int4 p; p.x = pk[0]; p.y = pk[1]; p.z = pk[2]; p.w = pk[3];
        myex[s] = p;   // lane-contiguous -> conflict-free ds_write_b128
    }
    // No barrier: wave-private slice; compiler's lgkmcnt covers write->read.

    // ---- main: 4 hl-pairs, 8 MFMA each (K=256, 240 used) ----
    const int dh = quad >> 1;            // which of the 2 packed out rows
    const int ob = (quad & 1) * 4;       // o base for this quad
    const float LN2B = 0.04620981f;      // ln2 / beta
    #pragma unroll
    for (int hp = 0; hp < 4; ++hp) {
        const int base = (2 * hp) * WCW + px;
        f32x4 acc0 = {0.0f, 0.0f, 0.0f, 0.0f};
        f32x4 acc1 = {0.0f, 0.0f, 0.0f, 0.0f};
        #pragma unroll
        for (int g = 0; g < NG; ++g) {
            s16x8 bfr = *(const s16x8*)&myex[base + toff[g]];
            if (g & 1)
                acc1 = __builtin_amdgcn_mfma_f32_16x16x32_bf16(
                           afrag[g], bfr, acc1, 0, 0, 0);
            else
                acc0 = __builtin_amdgcn_mfma_f32_16x16x32_bf16(
                           afrag[g], bfr, acc0, 0, 0, 0);
        }
        const int h = h0 + 2 * hp + dh;
        #pragma unroll
        for (int r = 0; r < 4; ++r) {
            float s = acc0[r] + acc1[r];
            // out = M + log2(s) * ln2/beta   (v_log_f32 is log2)
            out[((b * COUT + ob + r) * HH + h) * WW + w0 + px]
                = fmaf(__builtin_amdgcn_logf(s), LN2B, MSHIFT);
        }
    }
}

extern "C" void kernel_launch(void* const* d_in, const int* in_sizes, int n_in,
                              void* d_out, int out_size, void* d_ws, size_t ws_size,
                              hipStream_t stream) {
    const float* x   = (const float*)d_in[0];
    const float* wgt = (const float*)d_in[1];
    float* out  = (float*)d_out;

    const int B = in_sizes[0] / (CIN * HH * WW);              // 16
    const int nblk = B * (HH / TWH) * (WW / 64);              // 2048
    morph_mfma<<<nblk, 256, 0, stream>>>(x, wgt, out);
}

// Round 2
// 99.090 us; speedup vs baseline: 1.2340x; 1.2340x over previous
//
#include <hip/hip_runtime.h>
#include <hip/hip_bf16.h>
#include <math.h>

#define KW 5
#define BETA 15.0f
#define MSHIFT 3.0f
#define CIN 8
#define COUT 8
#define HH 256
#define WW 256
#define TWW 16     // wave tile width  (one 16-px MFMA N-group)
#define TWH 8      // wave tile height
#define WCW 20     // TWW + 4 halo
#define WCH 12     // TWH + 4 halo (rows 0..11 serve hl+tr up to 6+5=11)
#define WSLOTS (WCW * WCH)   // 240 slots/wave
#define NG 8       // K-groups: k=(tr 0..5, tc 0..4, c 0..7) = 240 pad 256

typedef float f32x4 __attribute__((ext_vector_type(4)));
typedef short s16x8 __attribute__((ext_vector_type(8)));

static __device__ __forceinline__ unsigned f2bf(float f) {
    unsigned u = __float_as_uint(f);
    return (u + 0x7FFFu + ((u >> 16) & 1u)) >> 16;  // RNE
}

// A-fragment table, exact MFMA A-layout, 2-ROW-PACKED:
//   rows 0-7 : A[o][k=(tr,tc,c)] = exp(beta*w[o][c][tr,tc])   (tr<=4; 0 at tr=5)
//   rows 8-15: A[8+o][k=(tr,tc,c)] = exp(beta*w[o][c][tr-1,tc]) (tr>=1; 0 at tr=0)
// With B[k][px] = EX[hl+tr][px+tc][c], D rows 0-7 = out row hl, rows 8-15 =
// out row hl+1 (index shift Sum_tr W[tr-1] EX[hl+tr] = Sum W[tr'] EX[hl+1+tr']).
// tap30 = g*4+quad in 0..31; 30,31 are zero-pad. 512 entries, 8192 B, L2-hot.
//
// R10 LESSON (do NOT retry): computing afrag in-kernel per-thread (64 loads +
// 64 __expf feeding the 32-VGPR afrag array) makes the allocator spill afrag
// to scratch (VGPR_Count 48, hbm 10% peak, kernel 8.6us -> 35-66us). The
// pre-kernel table + coalesced L2-hot load is the verified-fast form.
__global__ void build_afrag(const float* __restrict__ wgt,
                            s16x8* __restrict__ table) {
    int i = blockIdx.x * 64 + threadIdx.x;       // 0..511
    int g = i >> 6, lane = i & 63;
    int quad = lane >> 4, row = lane & 15;
    int tap30 = g * 4 + quad;
    int tr = tap30 / KW, tc = tap30 % KW;
    s16x8 af;
    #pragma unroll
    for (int j = 0; j < CIN; ++j) {              // j = c
        float v = 0.0f;
        if (tap30 < 30) {
            if (row < COUT) {
                if (tr <= 4)
                    v = __expf(BETA * wgt[(row * CIN + j) * (KW * KW) + tr * KW + tc]);
            } else {
                if (tr >= 1)
                    v = __expf(BETA * wgt[((row - 8) * CIN + j) * (KW * KW) + (tr - 1) * KW + tc]);
            }
        }
        af[j] = (short)f2bf(v);
    }
    table[i] = af;
}

// Exp-space 5x5 conv as implicit GEMM, wave-autonomous (R8), 2-row-packed (R9):
// out = M + log(sum exp(beta(x-M)) * exp(beta w)) / beta.
// Per hl-pair: 8 ds_read_b128 + 8 MFMA -> 16 px * 2 rows * 8 o  (R8 needed
// 14+14 for the same outputs). Epilogue full-exec: quad -> (dh=quad>>1,
// o=(quad&1)*4+reg).
// launch_bounds min-waves 5 -> ~102-VGPR cap (need ~85). NEVER 8: 64-cap
// spilled afrag in R4/R5 (VGPR_Count 32, 2-4x hbm traffic).
__global__ __launch_bounds__(256, 5) void morph_mfma(
    const float* __restrict__ x, const s16x8* __restrict__ table,
    float* __restrict__ out)
{
    __shared__ int4 exs[4 * WSLOTS];   // 4 waves * 3840 B = 15360 B

    const int tid  = threadIdx.x;
    const int lane = tid & 63;
    const int wv   = tid >> 6;
    const int px   = lane & 15;
    const int quad = lane >> 4;

    // XCD-contiguous swizzle: 2048 blocks = 8 XCD * 256; XCD k gets 2 batches.
    const int lid = blockIdx.x;
    const int sw  = (lid & 7) * 256 + (lid >> 3);
    const int b   = sw >> 7;
    const int t   = sw & 127;                 // 32 h-tiles * 4 w-tiles
    const int h0  = (t >> 2) * TWH;
    const int w0  = (t & 3) * 64 + wv * TWW;  // this wave's 16-px column

    int4* myex = &exs[wv * WSLOTS];

    // ---- A fragments: 8 coalesced 16-B loads (L2-hot table) ----
    s16x8 afrag[NG];
    int   toff[NG];
    #pragma unroll
    for (int g = 0; g < NG; ++g) {
        afrag[g] = table[g * 64 + lane];
        int tap30 = g * 4 + quad;
        int tcl   = tap30 < 30 ? tap30 : 29;  // clamp addr; A=0 kills pads
        toff[g] = (tcl / KW) * WCW + (tcl % KW);
    }

    // ---- stage exp(beta*(x-M)) for THIS WAVE's 20x12 halo ----
    for (int s = lane; s < WSLOTS; s += 64) {
        int r = s / WCW, col = s - r * WCW;
        int gh = h0 + r - 2, gw = w0 + col - 2;
        bool ok = ((unsigned)gh < (unsigned)HH) & ((unsigned)gw < (unsigned)WW);
        unsigned pk[4];
        #pragma unroll
        for (int c2 = 0; c2 < 4; ++c2) {
            float v0 = 0.0f, v1 = 0.0f;
            if (ok) {
                v0 = x[((b * CIN + 2 * c2) * HH + gh) * WW + gw];
                v1 = x[((b * CIN + 2 * c2 + 1) * HH + gh) * WW + gw];
            }
            // exp(beta*(v-M)) = 2^(v*beta*log2e - beta*M*log2e): 1 fma + v_exp
            float2 e = make_float2(
                __builtin_amdgcn_exp2f(fmaf(v0, 21.6404256f, -64.9212768f)),
                __builtin_amdgcn_exp2f(fmaf(v1, 21.6404256f, -64.9212768f)));
            __hip_bfloat162 h2 = __float22bfloat162_rn(e);
            pk[c2] = *reinterpret_cast<unsigned*>(&h2);
        }
        int4 p; p.x = pk[0]; p.y = pk[1]; p.z = pk[2]; p.w = pk[3];
        myex[s] = p;   // lane-contiguous -> conflict-free ds_write_b128
    }
    // No barrier: wave-private slice; compiler's lgkmcnt covers write->read.

    // ---- main: 4 hl-pairs, 8 MFMA each (K=256, 240 used) ----
    const int dh = quad >> 1;            // which of the 2 packed out rows
    const int ob = (quad & 1) * 4;       // o base for this quad
    const float LN2B = 0.04620981f;      // ln2 / beta
    #pragma unroll
    for (int hp = 0; hp < 4; ++hp) {
        const int base = (2 * hp) * WCW + px;
        f32x4 acc0 = {0.0f, 0.0f, 0.0f, 0.0f};
        f32x4 acc1 = {0.0f, 0.0f, 0.0f, 0.0f};
        #pragma unroll
        for (int g = 0; g < NG; ++g) {
            s16x8 bfr = *(const s16x8*)&myex[base + toff[g]];
            if (g & 1)
                acc1 = __builtin_amdgcn_mfma_f32_16x16x32_bf16(
                           afrag[g], bfr, acc1, 0, 0, 0);
            else
                acc0 = __builtin_amdgcn_mfma_f32_16x16x32_bf16(
                           afrag[g], bfr, acc0, 0, 0, 0);
        }
        const int h = h0 + 2 * hp + dh;
        #pragma unroll
        for (int r = 0; r < 4; ++r) {
            float s = acc0[r] + acc1[r];
            // out = M + log2(s) * ln2/beta   (v_log_f32 is log2)
            out[((b * COUT + ob + r) * HH + h) * WW + w0 + px]
                = fmaf(__builtin_amdgcn_logf(s), LN2B, MSHIFT);
        }
    }
}

extern "C" void kernel_launch(void* const* d_in, const int* in_sizes, int n_in,
                              void* d_out, int out_size, void* d_ws, size_t ws_size,
                              hipStream_t stream) {
    const float* x   = (const float*)d_in[0];
    const float* wgt = (const float*)d_in[1];
    float* out  = (float*)d_out;
    s16x8* tab  = (s16x8*)d_ws;   // 8192 B

    const int B = in_sizes[0] / (CIN * HH * WW);              // 16
    const int nblk = B * (HH / TWH) * (WW / 64);              // 2048
    build_afrag<<<NG, 64, 0, stream>>>(wgt, tab);
    morph_mfma<<<nblk, 256, 0, stream>>>(x, tab, out);
}